// Round 2
// baseline (995.773 us; speedup 1.0000x reference)
//
#include <hip/hip_runtime.h>
#include <math.h>

#define DIM   256
#define NUM_E 1024
#define HWN   1024          // 32*32 spatial per batch
#define NROW  32768         // 32*1024 flattened rows
#define NELEM 8388608       // 32*256*32*32
#define BETA  0.25f

#define RB    64            // rows per block in argmin
#define KC    64            // codebook chunk per LDS stage
#define LDST  68            // padded LDS row stride (floats); 272B = 16B-aligned

// ---------------------------------------------------------------------------
// numpy pairwise sum-of-squares, n=256: pairwise(a,128)+pairwise(a+128,128);
// each 128-block: 8 accumulators, r[j] += fl(a[i+j]^2), combine
// ((r0+r1)+(r2+r3))+((r4+r5)+(r6+r7)).  Square and add must round separately
// (numpy squares a temp array first) -> contraction off.
__device__ __forceinline__ float np_sumsq_256(const float* __restrict__ p,
                                              int stride) {
#pragma clang fp contract(off)
    float half[2];
#pragma unroll
    for (int h = 0; h < 2; ++h) {
        const float* a = p + h * 128 * stride;
        float r[8];
#pragma unroll
        for (int j = 0; j < 8; ++j) { const float v = a[j * stride]; r[j] = v * v; }
        for (int i = 8; i < 128; i += 8) {
#pragma unroll
            for (int j = 0; j < 8; ++j) {
                const float v = a[(i + j) * stride];
                r[j] += v * v;
            }
        }
        half[h] = ((r[0] + r[1]) + (r[2] + r[3])) + ((r[4] + r[5]) + (r[6] + r[7]));
    }
    return half[0] + half[1];
}

// ---------------------------------------------------------------------------
// ||e_k||^2 in numpy-f32 semantics, one thread per codebook row.
__global__ __launch_bounds__(256) void k_ee(const float* __restrict__ emb,
                                            float* __restrict__ ee) {
    const int k = blockIdx.x * 256 + threadIdx.x;
    if (k < NUM_E) ee[k] = np_sumsq_256(emb + (size_t)k * DIM, 1);
}

// ---------------------------------------------------------------------------
// fp32-bit-exact replication of the numpy nearest-codebook search:
//   dot  = sequential fma chain over d ascending  (BLAS sgemm microkernel)
//   dist = fl(fl(zz + ee_k) - fl(2*dot))
//   argmin: strict <, k ascending (first-index ties)
// Block: 256 threads = 16 row-slots x 16 k-slots, 4x4 register tile each.
__global__ __launch_bounds__(256, 1) void k_argmin(
        const float* __restrict__ z, const float* __restrict__ emb,
        const float* __restrict__ ee, float* __restrict__ oidx) {
    __shared__ __align__(16) char smem[139520];
    float* zT  = (float*)smem;               // [DIM][LDST]  zT[d][r]
    float* eT  = (float*)(smem + 69632);     // [DIM][LDST]  eT[d][kc^swz(d)]
    float* zzs = (float*)(smem + 139264);    // [RB]

    const int tid = threadIdx.x;
    const int R0  = blockIdx.x * RB;
    const int b   = R0 >> 10;
    const int hw0 = R0 & (HWN - 1);
    const float* zb = z + (size_t)b * DIM * HWN + hw0;   // z[b][d][hw0+r]

    // stage z tile: zT[d][r]  (coalesced 256B/wave, conflict-free LDS writes)
    for (int i = tid; i < RB * DIM; i += 256) {
        const int d = i >> 6, r = i & 63;
        zT[d * LDST + r] = zb[d * HWN + r];
    }
    __syncthreads();

    // zz[r] with numpy pairwise semantics (one thread per row)
    if (tid < RB) zzs[tid] = np_sumsq_256(zT + tid, LDST);

    const int rt = tid & 15, kt = tid >> 4;
    const int r0 = rt * 4,  c0 = kt * 4;

    float runv[4]; int runi[4];
#pragma unroll
    for (int i = 0; i < 4; ++i) { runv[i] = 1e30f; runi[i] = 0; }

    for (int k0 = 0; k0 < NUM_E; k0 += KC) {
        __syncthreads();   // protect eT readers of previous chunk (and zzs, iter 0)
        // stage codebook chunk transposed + XOR-swizzled (kills 8-way write conflict):
        // eT[d][kc ^ ((d&7)<<2)] = emb[k0+kc][d]; thread tid owns column d = tid.
        {
            const int d = tid;
            const int swz = (d & 7) << 2;
            const float* ecol = emb + (size_t)k0 * DIM + d;
            for (int kc = 0; kc < KC; ++kc)
                eT[d * LDST + (kc ^ swz)] = ecol[kc * DIM];   // coalesced global
        }
        __syncthreads();

        float acc[4][4];
#pragma unroll
        for (int i = 0; i < 4; ++i)
#pragma unroll
            for (int j = 0; j < 4; ++j) acc[i][j] = 0.f;

#pragma unroll 4
        for (int d = 0; d < DIM; ++d) {
            const float4 zv = *(const float4*)(zT + d * LDST + r0);
            const float4 ev = *(const float4*)(eT + d * LDST + (c0 ^ ((d & 7) << 2)));
            const float zd[4] = {zv.x, zv.y, zv.z, zv.w};
            const float ed[4] = {ev.x, ev.y, ev.z, ev.w};
#pragma unroll
            for (int i = 0; i < 4; ++i)
#pragma unroll
                for (int j = 0; j < 4; ++j)
                    acc[i][j] = fmaf(zd[i], ed[j], acc[i][j]);   // sequential-k chain
        }

        // min-update: k ascending within thread, strict < keeps first index
#pragma unroll
        for (int i = 0; i < 4; ++i) {
            const float zzv = zzs[r0 + i];
#pragma unroll
            for (int j = 0; j < 4; ++j) {
                const int k = k0 + c0 + j;
                const float t    = zzv + ee[k];        // fl(zz + ee)
                const float dist = t - 2.0f * acc[i][j]; // fl(t - 2*dot)
                if (dist < runv[i]) { runv[i] = dist; runi[i] = k; }
            }
        }
    }

    // cross-thread (16 k-slot) reduce per row, index tie-break (exact f32 ties!)
    __syncthreads();
    float* minv = (float*)(smem + 69632);
    int*   mini = (int*)  (smem + 69632 + 4096);
#pragma unroll
    for (int i = 0; i < 4; ++i) {
        minv[(r0 + i) * 16 + kt] = runv[i];
        mini[(r0 + i) * 16 + kt] = runi[i];
    }
    __syncthreads();
    if (tid < RB) {
        float bv = 1e30f; int bi = NUM_E;
        for (int t = 0; t < 16; ++t) {
            const float v  = minv[tid * 16 + t];
            const int   ix = mini[tid * 16 + t];
            if (v < bv || (v == bv && ix < bi)) { bv = v; bi = ix; }
        }
        oidx[R0 + tid] = (float)bi;
    }
}

// ---------------------------------------------------------------------------
__global__ void k_zero(float4* __restrict__ p, int n4) {
    int i = blockIdx.x * blockDim.x + threadIdx.x;
    const int stride = gridDim.x * blockDim.x;
    for (; i < n4; i += stride) p[i] = make_float4(0.f, 0.f, 0.f, 0.f);
}

__global__ __launch_bounds__(256) void k_scatter(const float* __restrict__ idxf,
                                                 float* __restrict__ enc) {
    const int n = blockIdx.x * 256 + threadIdx.x;
    const int k = (int)idxf[n];
    enc[(size_t)n * NUM_E + k] = 1.0f;
}

// z_q (straight-through, numpy op order) + loss partial sum
__global__ __launch_bounds__(256) void k_zq(const float* __restrict__ z,
                                            const float* __restrict__ emb,
                                            const float* __restrict__ idxf,
                                            float* __restrict__ ozq,
                                            double* __restrict__ loss) {
    const int gid = blockIdx.x * 256 + threadIdx.x;   // NELEM/4 threads
    const int hw4 = gid & 255;
    const int d   = (gid >> 8) & 255;
    const int b   = gid >> 16;
    const size_t zoff = ((size_t)(b * DIM + d)) * HWN + hw4 * 4;
    const float4 zv = *(const float4*)(z + zoff);
    const int n0 = b * HWN + hw4 * 4;
    const int i0 = (int)idxf[n0 + 0], i1 = (int)idxf[n0 + 1];
    const int i2 = (int)idxf[n0 + 2], i3 = (int)idxf[n0 + 3];
    const float e0 = emb[i0 * DIM + d], e1 = emb[i1 * DIM + d];
    const float e2 = emb[i2 * DIM + d], e3 = emb[i3 * DIM + d];
    // t = fl(e - z);  out = fl(z + t)   (matches z + stopgrad(z_q - z))
    const float t0 = e0 - zv.x, t1 = e1 - zv.y, t2 = e2 - zv.z, t3 = e3 - zv.w;
    const float4 o = make_float4(zv.x + t0, zv.y + t1, zv.z + t2, zv.w + t3);
    *(float4*)(ozq + zoff) = o;
    double s = (double)t0 * t0 + (double)t1 * t1 + (double)t2 * t2 + (double)t3 * t3;
#pragma unroll
    for (int off = 32; off > 0; off >>= 1) s += __shfl_down(s, off, 64);
    if ((threadIdx.x & 63) == 0) atomicAdd(loss, s);
}

__global__ void k_fin(const double* __restrict__ loss, float* __restrict__ out) {
    const float m = (float)(loss[0] / 8388608.0);   // /2^23 exact scaling
    out[0] = m + BETA * m;
}

// ---------------------------------------------------------------------------
extern "C" void kernel_launch(void* const* d_in, const int* in_sizes, int n_in,
                              void* d_out, int out_size, void* d_ws, size_t ws_size,
                              hipStream_t stream) {
    const float* z   = (const float*)d_in[0];
    const float* emb = (const float*)d_in[1];
    float* out   = (float*)d_out;
    float* o_zq  = out + 1;                              // 8,388,608
    float* o_enc = o_zq + NELEM;                         // 33,554,432
    float* o_idx = o_enc + (size_t)NROW * NUM_E;         // 32,768

    float*  ws_ee   = (float*)d_ws;                      // 4 KB
    double* ws_loss = (double*)((char*)d_ws + 8192);     // 8 B

    hipMemsetAsync(ws_loss, 0, sizeof(double), stream);
    k_ee     <<<NUM_E / 256, 256, 0, stream>>>(emb, ws_ee);
    k_argmin <<<NROW / RB, 256, 0, stream>>>(z, emb, ws_ee, o_idx);
    k_zero   <<<2048, 256, 0, stream>>>((float4*)o_enc, (NROW * NUM_E) / 4);
    k_scatter<<<NROW / 256, 256, 0, stream>>>(o_idx, o_enc);
    k_zq     <<<NELEM / 4 / 256, 256, 0, stream>>>(z, emb, o_idx, o_zq, ws_loss);
    k_fin    <<<1, 1, 0, stream>>>(ws_loss, out);
}

// Round 3
// 474.046 us; speedup vs baseline: 2.1006x; 2.1006x over previous
//
#include <hip/hip_runtime.h>
#include <math.h>

#define DIM   256
#define NUM_E 1024
#define HWN   1024          // 32*32 spatial per batch
#define NROW  32768         // 32*1024 flattened rows
#define NELEM 8388608       // 32*256*32*32

#define BM 128
#define BN 128
#define BK 32
#define NCH 8               // NUM_E / BN candidate chunks

// ---------------------------------------------------------------------------
// numpy pairwise sum-of-squares, n=256: pairwise(a,128)+pairwise(a+128,128);
// each 128-block: 8 accumulators r[j] += fl(a[i+j]^2), combine
// ((r0+r1)+(r2+r3))+((r4+r5)+(r6+r7)).  Square/add round separately.
__device__ __forceinline__ float np_sumsq_256(const float* __restrict__ p,
                                              int stride) {
#pragma clang fp contract(off)
    float half[2];
#pragma unroll
    for (int h = 0; h < 2; ++h) {
        const float* a = p + h * 128 * stride;
        float r[8];
#pragma unroll
        for (int j = 0; j < 8; ++j) { const float v = a[j * stride]; r[j] = v * v; }
        for (int i = 8; i < 128; i += 8) {
#pragma unroll
            for (int j = 0; j < 8; ++j) {
                const float v = a[(i + j) * stride];
                r[j] += v * v;
            }
        }
        half[h] = ((r[0] + r[1]) + (r[2] + r[3])) + ((r[4] + r[5]) + (r[6] + r[7]));
    }
    return half[0] + half[1];
}

// ||e_k||^2, one thread per codebook row (contiguous)
__global__ __launch_bounds__(256) void k_ee(const float* __restrict__ emb,
                                            float* __restrict__ ee) {
    const int k = blockIdx.x * 256 + threadIdx.x;
    ee[k] = np_sumsq_256(emb + (size_t)k * DIM, 1);
}

// ||z_r||^2, one thread per flat row (stride HWN; coalesced across threads)
__global__ __launch_bounds__(256) void k_zz(const float* __restrict__ z,
                                            float* __restrict__ zz) {
    const int r  = blockIdx.x * 256 + threadIdx.x;
    const int b  = r >> 10, hw = r & (HWN - 1);
    zz[r] = np_sumsq_256(z + (size_t)b * DIM * HWN + hw, HWN);
}

// ---------------------------------------------------------------------------
// GEMM-tiled bit-exact distance + per-chunk argmin candidates.
// BM=128 x BN=128 x BK=32, 256 threads, 8x8 microtile; dot = sequential fmaf
// chain over d ascending; dist = fl(fl(zz+ee) - fl(2*dot)); strict-< argmin.
__global__ __launch_bounds__(256, 3) void k_gemm(
        const float* __restrict__ z, const float* __restrict__ emb,
        const float* __restrict__ zzg, const float* __restrict__ eeg,
        float* __restrict__ cv, int* __restrict__ ci) {
    __shared__ __align__(16) float zs[BK * BM];   // zs[k][m], row stride 128
    __shared__ __align__(16) float es[BK * BN];   // es[k][slot^swz]
    float4* zs4 = (float4*)zs;
    float4* es4 = (float4*)es;

    const int tid = threadIdx.x;
    const int nb  = blockIdx.x & (NCH - 1);
    const int mb  = blockIdx.x >> 3;
    const int R0  = mb * BM;
    const int b   = R0 >> 10;
    const int hw0 = R0 & (HWN - 1);

    const int tx = tid & 15, ty = tid >> 4;
    const int sA = (2 * tx)     ^ (tx >> 2);     // es read slots (constant)
    const int sB = (2 * tx + 1) ^ (tx >> 2);
    const int kg = tid & 7, ng = tid >> 3;       // es staging ownership
    const int wslot = ng ^ (ng >> 3);
    const int m4 = tid & 31, kzb = tid >> 5;     // zs staging ownership

    const float* zbase = z + (size_t)b * DIM * HWN + hw0;
    const float4* embq = (const float4*)(emb + ((size_t)nb * BN + ng * 4) * DIM);

    float acc[8][8];
#pragma unroll
    for (int i = 0; i < 8; ++i)
#pragma unroll
        for (int j = 0; j < 8; ++j) acc[i][j] = 0.f;

    for (int k0 = 0; k0 < DIM; k0 += BK) {
        __syncthreads();
        // stage zs[k][m] = z[b][k0+k][hw0+m] (already k-major; coalesced)
#pragma unroll
        for (int q = 0; q < 4; ++q) {
            const int k = q * 8 + kzb;
            zs4[k * 32 + m4] =
                *(const float4*)(zbase + (size_t)(k0 + k) * HWN + m4 * 4);
        }
        // stage es[k][n] = emb[nb*128+n][k0+k] via register transpose
        {
            float4 g0 = embq[0 * 64 + (k0 >> 2) + kg];
            float4 g1 = embq[1 * 64 + (k0 >> 2) + kg];
            float4 g2 = embq[2 * 64 + (k0 >> 2) + kg];
            float4 g3 = embq[3 * 64 + (k0 >> 2) + kg];
            es4[(kg * 4 + 0) * 32 + wslot] = make_float4(g0.x, g1.x, g2.x, g3.x);
            es4[(kg * 4 + 1) * 32 + wslot] = make_float4(g0.y, g1.y, g2.y, g3.y);
            es4[(kg * 4 + 2) * 32 + wslot] = make_float4(g0.z, g1.z, g2.z, g3.z);
            es4[(kg * 4 + 3) * 32 + wslot] = make_float4(g0.w, g1.w, g2.w, g3.w);
        }
        __syncthreads();

#pragma unroll 4
        for (int k = 0; k < BK; ++k) {
            const float4 za0 = zs4[k * 32 + ty * 2];
            const float4 za1 = zs4[k * 32 + ty * 2 + 1];
            const float4 eb0 = es4[k * 32 + sA];
            const float4 eb1 = es4[k * 32 + sB];
            const float zf[8] = {za0.x, za0.y, za0.z, za0.w,
                                 za1.x, za1.y, za1.z, za1.w};
            const float ef[8] = {eb0.x, eb0.y, eb0.z, eb0.w,
                                 eb1.x, eb1.y, eb1.z, eb1.w};
#pragma unroll
            for (int i = 0; i < 8; ++i)
#pragma unroll
                for (int j = 0; j < 8; ++j)
                    acc[i][j] = fmaf(zf[i], ef[j], acc[i][j]);
        }
    }

    // epilogue: dist + per-row argmin over this block's 128 cols
    const int n0g = nb * BN + tx * 8;
#pragma unroll
    for (int i = 0; i < 8; ++i) {
        const int r = R0 + ty * 8 + i;
        const float zzv = zzg[r];
        float bv = 1e30f; int bi = 0;
#pragma unroll
        for (int j = 0; j < 8; ++j) {
            const int kk = n0g + j;
            const float t    = zzv + eeg[kk];
            const float dist = t - 2.0f * acc[i][j];
            if (dist < bv) { bv = dist; bi = kk; }
        }
#pragma unroll
        for (int off = 1; off <= 8; off <<= 1) {
            const float v2 = __shfl_xor(bv, off, 64);
            const int   i2 = __shfl_xor(bi, off, 64);
            if (v2 < bv || (v2 == bv && i2 < bi)) { bv = v2; bi = i2; }
        }
        if (tx == 0) {
            cv[(size_t)nb * NROW + r] = bv;
            ci[(size_t)nb * NROW + r] = bi;
        }
    }
}

// final candidate reduce: 8 chunks (ascending k) per row
__global__ __launch_bounds__(256) void k_amfin(const float* __restrict__ cv,
                                               const int* __restrict__ ci,
                                               float* __restrict__ oidx) {
    const int r = blockIdx.x * 256 + threadIdx.x;
    float bv = cv[r]; int bi = ci[r];
#pragma unroll
    for (int c = 1; c < NCH; ++c) {
        const float v = cv[(size_t)c * NROW + r];
        const int   x = ci[(size_t)c * NROW + r];
        if (v < bv || (v == bv && x < bi)) { bv = v; bi = x; }
    }
    oidx[r] = (float)bi;
}

// ---------------------------------------------------------------------------
__global__ void k_zero(float4* __restrict__ p, int n4) {
    int i = blockIdx.x * blockDim.x + threadIdx.x;
    const int stride = gridDim.x * blockDim.x;
    for (; i < n4; i += stride) p[i] = make_float4(0.f, 0.f, 0.f, 0.f);
}

__global__ __launch_bounds__(256) void k_scatter(const float* __restrict__ idxf,
                                                 float* __restrict__ enc) {
    const int n = blockIdx.x * 256 + threadIdx.x;
    const int k = (int)idxf[n];
    enc[(size_t)n * NUM_E + k] = 1.0f;
}

// z_q (straight-through, numpy op order) + per-block loss partial (no atomics)
__global__ __launch_bounds__(256) void k_zq(const float* __restrict__ z,
                                            const float* __restrict__ emb,
                                            const float* __restrict__ idxf,
                                            float* __restrict__ ozq,
                                            double* __restrict__ partials) {
    const int gid = blockIdx.x * 256 + threadIdx.x;   // NELEM/4 threads
    const int hw4 = gid & 255;
    const int d   = (gid >> 8) & 255;
    const int b   = gid >> 16;
    const size_t zoff = ((size_t)(b * DIM + d)) * HWN + hw4 * 4;
    const float4 zv = *(const float4*)(z + zoff);
    const int n0 = b * HWN + hw4 * 4;
    const int i0 = (int)idxf[n0 + 0], i1 = (int)idxf[n0 + 1];
    const int i2 = (int)idxf[n0 + 2], i3 = (int)idxf[n0 + 3];
    const float e0 = emb[i0 * DIM + d], e1 = emb[i1 * DIM + d];
    const float e2 = emb[i2 * DIM + d], e3 = emb[i3 * DIM + d];
    const float t0 = e0 - zv.x, t1 = e1 - zv.y, t2 = e2 - zv.z, t3 = e3 - zv.w;
    const float4 o = make_float4(zv.x + t0, zv.y + t1, zv.z + t2, zv.w + t3);
    *(float4*)(ozq + zoff) = o;
    double s = (double)t0 * t0 + (double)t1 * t1 + (double)t2 * t2 + (double)t3 * t3;
#pragma unroll
    for (int off = 32; off > 0; off >>= 1) s += __shfl_down(s, off, 64);
    __shared__ double pw[4];
    if ((threadIdx.x & 63) == 0) pw[threadIdx.x >> 6] = s;
    __syncthreads();
    if (threadIdx.x == 0)
        partials[blockIdx.x] = (pw[0] + pw[1]) + (pw[2] + pw[3]);
}

__global__ __launch_bounds__(256) void k_fin(const double* __restrict__ partials,
                                             float* __restrict__ out) {
    const int t = threadIdx.x;
    double s = 0.0;
    for (int i = t; i < 8192; i += 256) s += partials[i];
#pragma unroll
    for (int off = 32; off > 0; off >>= 1) s += __shfl_down(s, off, 64);
    __shared__ double w[4];
    if ((t & 63) == 0) w[t >> 6] = s;
    __syncthreads();
    if (t == 0) {
        const double tot = (w[0] + w[1]) + (w[2] + w[3]);
        const float m = (float)(tot / 8388608.0);   // /2^23 exact
        out[0] = m + 0.25f * m;
    }
}

// ---------------------------------------------------------------------------
extern "C" void kernel_launch(void* const* d_in, const int* in_sizes, int n_in,
                              void* d_out, int out_size, void* d_ws, size_t ws_size,
                              hipStream_t stream) {
    const float* z   = (const float*)d_in[0];
    const float* emb = (const float*)d_in[1];
    float* out   = (float*)d_out;
    float* o_zq  = out + 1;                              // 8,388,608
    float* o_enc = o_zq + NELEM;                         // 33,554,432
    float* o_idx = o_enc + (size_t)NROW * NUM_E;         // 32,768

    // scratch inside the enc output region (zeroed by k_zero AFTER all reads)
    float*  s_cv = o_enc;                                // 8*32768
    int*    s_ci = (int*)(o_enc + 262144);               // 8*32768
    float*  s_zz = o_enc + 524288;                       // 32768
    float*  s_ee = o_enc + 557056;                       // 1024
    double* s_ps = (double*)(o_enc + 558080);            // 8192 doubles

    k_ee     <<<NUM_E / 256, 256, 0, stream>>>(emb, s_ee);
    k_zz     <<<NROW / 256, 256, 0, stream>>>(z, s_zz);
    k_gemm   <<<(NROW / BM) * NCH, 256, 0, stream>>>(z, emb, s_zz, s_ee, s_cv, s_ci);
    k_amfin  <<<NROW / 256, 256, 0, stream>>>(s_cv, s_ci, o_idx);
    k_zq     <<<NELEM / 4 / 256, 256, 0, stream>>>(z, emb, o_idx, o_zq, s_ps);
    k_fin    <<<1, 256, 0, stream>>>(s_ps, out);
    k_zero   <<<2048, 256, 0, stream>>>((float4*)o_enc, (NROW * NUM_E) / 4);
    k_scatter<<<NROW / 256, 256, 0, stream>>>(o_idx, o_enc);
}

// Round 4
// 446.055 us; speedup vs baseline: 2.2324x; 1.0628x over previous
//
#include <hip/hip_runtime.h>
#include <math.h>

#define DIM   256
#define NUM_E 1024
#define HWN   1024          // 32*32 spatial per batch
#define NROW  32768         // 32*1024 flattened rows
#define NELEM 8388608       // 32*256*32*32

#define BM 128
#define BN 128
#define BK 32
#define NCH 8               // NUM_E / BN candidate chunks

// ---------------------------------------------------------------------------
// numpy pairwise sum-of-squares, n=256: pairwise(a,128)+pairwise(a+128,128);
// each 128-half: 8 accumulators r[j] += fl(a[i+j]^2), combined
// ((r0+r1)+(r2+r3))+((r4+r5)+(r6+r7)); halves added last.  The two halves are
// INDEPENDENT chains -> interleave them for 16-deep load ILP (bit-identical).
__device__ __forceinline__ float np_sumsq_256i(const float* __restrict__ p,
                                               int stride) {
#pragma clang fp contract(off)
    const float* a0 = p;
    const float* a1 = p + 128 * stride;
    float r0[8], r1[8];
#pragma unroll
    for (int j = 0; j < 8; ++j) {
        const float v = a0[j * stride]; r0[j] = v * v;
        const float w = a1[j * stride]; r1[j] = w * w;
    }
    for (int i = 8; i < 128; i += 8) {
#pragma unroll
        for (int j = 0; j < 8; ++j) {
            const float v = a0[(i + j) * stride]; r0[j] += v * v;
            const float w = a1[(i + j) * stride]; r1[j] += w * w;
        }
    }
    const float h0 = ((r0[0] + r0[1]) + (r0[2] + r0[3])) + ((r0[4] + r0[5]) + (r0[6] + r0[7]));
    const float h1 = ((r1[0] + r1[1]) + (r1[2] + r1[3])) + ((r1[4] + r1[5]) + (r1[6] + r1[7]));
    return h0 + h1;
}

// merged ||z_r||^2 (blocks 0..127) and ||e_k||^2 (blocks 128..131)
__global__ __launch_bounds__(256) void k_pre(const float* __restrict__ z,
                                             const float* __restrict__ emb,
                                             float* __restrict__ zz,
                                             float* __restrict__ ee) {
    const int bid = blockIdx.x;
    if (bid < 128) {
        const int r = bid * 256 + threadIdx.x;
        const int b = r >> 10, hw = r & (HWN - 1);
        zz[r] = np_sumsq_256i(z + (size_t)b * DIM * HWN + hw, HWN);
    } else {
        const int k = (bid - 128) * 256 + threadIdx.x;
        ee[k] = np_sumsq_256i(emb + (size_t)k * DIM, 1);
    }
}

// ---------------------------------------------------------------------------
// GEMM-tiled bit-exact distance + per-chunk argmin candidates.
// BM=128 x BN=128 x BK=32, 256 threads, 8x8 microtile; dot = sequential fmaf
// chain over d ascending; dist = fl(fl(zz+ee) - fl(2*dot)); strict-< argmin.
// es LDS layout: es4[k*32 + (c ^ ((k>>2)&7))] holds column-group c (4 cols).
// Write side: thread (kg=tid&7, ng=tid>>3) -> slot ng^kg: per quarter-wave
// every bank-group gets exactly 2 writes (2-way = free).  Reads likewise 2-way.
__global__ __launch_bounds__(256, 3) void k_gemm(
        const float* __restrict__ z, const float* __restrict__ emb,
        const float* __restrict__ zzg, const float* __restrict__ eeg,
        float* __restrict__ cv, int* __restrict__ ci) {
    __shared__ __align__(16) float zs[BK * BM];   // zs[k][m], row stride 128
    __shared__ __align__(16) float es[BK * BN];   // es[k][slot], swizzled
    float4* zs4 = (float4*)zs;
    float4* es4 = (float4*)es;

    const int tid = threadIdx.x;
    const int nb  = blockIdx.x & (NCH - 1);
    const int mb  = blockIdx.x >> 3;
    const int R0  = mb * BM;
    const int b   = R0 >> 10;
    const int hw0 = R0 & (HWN - 1);

    const int tx = tid & 15, ty = tid >> 4;
    const int kg = tid & 7, ng = tid >> 3;       // es staging ownership
    const int wslot = ng ^ kg;                   // conflict-free write slot
    const int m4 = tid & 31, kzb = tid >> 5;     // zs staging ownership

    const float* zbase = z + (size_t)b * DIM * HWN + hw0;
    const float4* embq = (const float4*)(emb + ((size_t)nb * BN + ng * 4) * DIM);

    float acc[8][8];
#pragma unroll
    for (int i = 0; i < 8; ++i)
#pragma unroll
        for (int j = 0; j < 8; ++j) acc[i][j] = 0.f;

    for (int k0 = 0; k0 < DIM; k0 += BK) {
        __syncthreads();
        // stage zs[k][m] = z[b][k0+k][hw0+m] (k-major already; coalesced)
#pragma unroll
        for (int q = 0; q < 4; ++q) {
            const int k = q * 8 + kzb;
            zs4[k * 32 + m4] =
                *(const float4*)(zbase + (size_t)(k0 + k) * HWN + m4 * 4);
        }
        // stage es rows kg*4..kg*4+3, column-group ng, via register transpose
        {
            const float4 g0 = embq[0 * 64 + (k0 >> 2) + kg];
            const float4 g1 = embq[1 * 64 + (k0 >> 2) + kg];
            const float4 g2 = embq[2 * 64 + (k0 >> 2) + kg];
            const float4 g3 = embq[3 * 64 + (k0 >> 2) + kg];
            es4[(kg * 4 + 0) * 32 + wslot] = make_float4(g0.x, g1.x, g2.x, g3.x);
            es4[(kg * 4 + 1) * 32 + wslot] = make_float4(g0.y, g1.y, g2.y, g3.y);
            es4[(kg * 4 + 2) * 32 + wslot] = make_float4(g0.z, g1.z, g2.z, g3.z);
            es4[(kg * 4 + 3) * 32 + wslot] = make_float4(g0.w, g1.w, g2.w, g3.w);
        }
        __syncthreads();

#pragma unroll
        for (int k4 = 0; k4 < 8; ++k4) {
            const int sA = (2 * tx) ^ k4;        // column-group 2tx at these rows
            const int sB = sA ^ 1;               // column-group 2tx+1
#pragma unroll
            for (int kj = 0; kj < 4; ++kj) {
                const int k = k4 * 4 + kj;
                const float4 za0 = zs4[k * 32 + ty * 2];
                const float4 za1 = zs4[k * 32 + ty * 2 + 1];
                const float4 eb0 = es4[k * 32 + sA];
                const float4 eb1 = es4[k * 32 + sB];
                const float zf[8] = {za0.x, za0.y, za0.z, za0.w,
                                     za1.x, za1.y, za1.z, za1.w};
                const float ef[8] = {eb0.x, eb0.y, eb0.z, eb0.w,
                                     eb1.x, eb1.y, eb1.z, eb1.w};
#pragma unroll
                for (int i = 0; i < 8; ++i)
#pragma unroll
                    for (int j = 0; j < 8; ++j)
                        acc[i][j] = fmaf(zf[i], ef[j], acc[i][j]);
            }
        }
    }

    // epilogue: dist + per-row argmin over this block's 128 cols
    const int n0g = nb * BN + tx * 8;
#pragma unroll
    for (int i = 0; i < 8; ++i) {
        const int r = R0 + ty * 8 + i;
        const float zzv = zzg[r];
        float bv = 1e30f; int bi = 0;
#pragma unroll
        for (int j = 0; j < 8; ++j) {
            const int kk = n0g + j;
            const float t    = zzv + eeg[kk];
            const float dist = t - 2.0f * acc[i][j];
            if (dist < bv) { bv = dist; bi = kk; }
        }
#pragma unroll
        for (int off = 1; off <= 8; off <<= 1) {
            const float v2 = __shfl_xor(bv, off, 64);
            const int   i2 = __shfl_xor(bi, off, 64);
            if (v2 < bv || (v2 == bv && i2 < bi)) { bv = v2; bi = i2; }
        }
        if (tx == 0) {
            cv[(size_t)nb * NROW + r] = bv;
            ci[(size_t)nb * NROW + r] = bi;
        }
    }
}

// final candidate reduce (8 chunks ascending) + optional fused one-hot scatter
__global__ __launch_bounds__(256) void k_amfin(const float* __restrict__ cv,
                                               const int* __restrict__ ci,
                                               float* __restrict__ oidx,
                                               float* __restrict__ enc,
                                               int do_scatter) {
    const int r = blockIdx.x * 256 + threadIdx.x;
    float bv = cv[r]; int bi = ci[r];
#pragma unroll
    for (int c = 1; c < NCH; ++c) {
        const float v = cv[(size_t)c * NROW + r];
        const int   x = ci[(size_t)c * NROW + r];
        if (v < bv || (v == bv && x < bi)) { bv = v; bi = x; }
    }
    oidx[r] = (float)bi;
    if (do_scatter) enc[(size_t)r * NUM_E + bi] = 1.0f;
}

// ---------------------------------------------------------------------------
__global__ void k_zero(float4* __restrict__ p, int n4) {
    int i = blockIdx.x * blockDim.x + threadIdx.x;
    const int stride = gridDim.x * blockDim.x;
    for (; i < n4; i += stride) p[i] = make_float4(0.f, 0.f, 0.f, 0.f);
}

__global__ __launch_bounds__(256) void k_scatter(const float* __restrict__ idxf,
                                                 float* __restrict__ enc) {
    const int n = blockIdx.x * 256 + threadIdx.x;
    const int k = (int)idxf[n];
    enc[(size_t)n * NUM_E + k] = 1.0f;
}

// z_q (straight-through, numpy op order) + per-block loss partial (no atomics)
__global__ __launch_bounds__(256) void k_zq(const float* __restrict__ z,
                                            const float* __restrict__ emb,
                                            const float* __restrict__ idxf,
                                            float* __restrict__ ozq,
                                            double* __restrict__ partials) {
    const int gid = blockIdx.x * 256 + threadIdx.x;   // NELEM/4 threads
    const int hw4 = gid & 255;
    const int d   = (gid >> 8) & 255;
    const int b   = gid >> 16;
    const size_t zoff = ((size_t)(b * DIM + d)) * HWN + hw4 * 4;
    const float4 zv = *(const float4*)(z + zoff);
    const int n0 = b * HWN + hw4 * 4;
    const int i0 = (int)idxf[n0 + 0], i1 = (int)idxf[n0 + 1];
    const int i2 = (int)idxf[n0 + 2], i3 = (int)idxf[n0 + 3];
    const float e0 = emb[i0 * DIM + d], e1 = emb[i1 * DIM + d];
    const float e2 = emb[i2 * DIM + d], e3 = emb[i3 * DIM + d];
    const float t0 = e0 - zv.x, t1 = e1 - zv.y, t2 = e2 - zv.z, t3 = e3 - zv.w;
    const float4 o = make_float4(zv.x + t0, zv.y + t1, zv.z + t2, zv.w + t3);
    *(float4*)(ozq + zoff) = o;
    double s = (double)t0 * t0 + (double)t1 * t1 + (double)t2 * t2 + (double)t3 * t3;
#pragma unroll
    for (int off = 32; off > 0; off >>= 1) s += __shfl_down(s, off, 64);
    __shared__ double pw[4];
    if ((threadIdx.x & 63) == 0) pw[threadIdx.x >> 6] = s;
    __syncthreads();
    if (threadIdx.x == 0)
        partials[blockIdx.x] = (pw[0] + pw[1]) + (pw[2] + pw[3]);
}

__global__ __launch_bounds__(256) void k_fin(const double* __restrict__ partials,
                                             float* __restrict__ out) {
    const int t = threadIdx.x;
    double s = 0.0;
    for (int i = t; i < 8192; i += 256) s += partials[i];
#pragma unroll
    for (int off = 32; off > 0; off >>= 1) s += __shfl_down(s, off, 64);
    __shared__ double w[4];
    if ((t & 63) == 0) w[t >> 6] = s;
    __syncthreads();
    if (t == 0) {
        const double tot = (w[0] + w[1]) + (w[2] + w[3]);
        const float m = (float)(tot / 8388608.0);   // /2^23 exact
        out[0] = m + 0.25f * m;
    }
}

// ---------------------------------------------------------------------------
extern "C" void kernel_launch(void* const* d_in, const int* in_sizes, int n_in,
                              void* d_out, int out_size, void* d_ws, size_t ws_size,
                              hipStream_t stream) {
    const float* z   = (const float*)d_in[0];
    const float* emb = (const float*)d_in[1];
    float* out   = (float*)d_out;
    float* o_zq  = out + 1;                              // 8,388,608
    float* o_enc = o_zq + NELEM;                         // 33,554,432
    float* o_idx = o_enc + (size_t)NROW * NUM_E;         // 32,768

    const size_t need_bytes = (size_t)(262144 + 262144 + 32768 + 1024) * 4
                            + (size_t)8192 * 8 + 64;     // ~2.3 MB

    if (ws_size >= need_bytes) {
        // scratch in d_ws; zero first; scatter fused into k_amfin
        float*  s_cv = (float*)d_ws;                     // 262144
        int*    s_ci = (int*)(s_cv + 262144);            // 262144
        float*  s_zz = (float*)(s_ci + 262144);          // 32768
        float*  s_ee = s_zz + 32768;                     // 1024
        double* s_ps = (double*)(s_ee + 1024);           // 8192 (8B-aligned)

        k_zero  <<<2048, 256, 0, stream>>>((float4*)o_enc, (NROW * NUM_E) / 4);
        k_pre   <<<132, 256, 0, stream>>>(z, emb, s_zz, s_ee);
        k_gemm  <<<(NROW / BM) * NCH, 256, 0, stream>>>(z, emb, s_zz, s_ee, s_cv, s_ci);
        k_amfin <<<NROW / 256, 256, 0, stream>>>(s_cv, s_ci, o_idx, o_enc, 1);
        k_zq    <<<NELEM / 4 / 256, 256, 0, stream>>>(z, emb, o_idx, o_zq, s_ps);
        k_fin   <<<1, 256, 0, stream>>>(s_ps, out);
    } else {
        // fallback: scratch inside o_enc (zeroed after all reads), late scatter
        float*  s_cv = o_enc;
        int*    s_ci = (int*)(o_enc + 262144);
        float*  s_zz = o_enc + 524288;
        float*  s_ee = o_enc + 557056;
        double* s_ps = (double*)(o_enc + 558080);

        k_pre   <<<132, 256, 0, stream>>>(z, emb, s_zz, s_ee);
        k_gemm  <<<(NROW / BM) * NCH, 256, 0, stream>>>(z, emb, s_zz, s_ee, s_cv, s_ci);
        k_amfin <<<NROW / 256, 256, 0, stream>>>(s_cv, s_ci, o_idx, o_enc, 0);
        k_zq    <<<NELEM / 4 / 256, 256, 0, stream>>>(z, emb, o_idx, o_zq, s_ps);
        k_fin   <<<1, 256, 0, stream>>>(s_ps, out);
        k_zero  <<<2048, 256, 0, stream>>>((float4*)o_enc, (NROW * NUM_E) / 4);
        k_scatter<<<NROW / 256, 256, 0, stream>>>(o_idx, o_enc);
    }
}